// Round 18
// baseline (63.952 us; speedup 1.0000x reference)
//
#include <hip/hip_runtime.h>

typedef __attribute__((ext_vector_type(8))) short short8;
typedef __attribute__((ext_vector_type(4))) float f32x4;

#define S_LEN 1024
#define B_N 8
#define D_DIM 512
#define SLAB 4194304    // 8192*512 elements per tfm slab
#define NX   4194304    // x element count

static __device__ __forceinline__ unsigned short f2bf(float f){
  unsigned int u = __float_as_uint(f);
  u = u + 0x7fffu + ((u>>16)&1u);
  return (unsigned short)(u>>16);
}
static __device__ __forceinline__ float bf2f(unsigned short h){
  return __uint_as_float(((unsigned int)h)<<16);
}
static __device__ __forceinline__ ushort4 cvt4(float4 v){
  ushort4 h; h.x=f2bf(v.x); h.y=f2bf(v.y); h.z=f2bf(v.z); h.w=f2bf(v.w); return h;
}

#define GLL16(g,l) __builtin_amdgcn_global_load_lds( \
    (__attribute__((address_space(1))) void*)(g), \
    (__attribute__((address_space(3))) void*)(l), 16, 0, 0)

// hard barrier: compiler memory barrier + ISA barrier + sched fence both sides
#define SBAR() do { __builtin_amdgcn_sched_barrier(0); \
  asm volatile("s_barrier" ::: "memory"); \
  __builtin_amdgcn_sched_barrier(0); } while(0)
#define VMCNT(n) asm volatile("s_waitcnt vmcnt(" #n ")" ::: "memory")

// ---------------- conv: x and W -> bf16, 4-deep ILP per thread ----------------
__global__ __launch_bounds__(256) void k_conv(const float* __restrict__ x,
    const float* __restrict__ W, unsigned short* __restrict__ xbf,
    unsigned short* __restrict__ wbf)
{
  int tid = blockIdx.x*256 + threadIdx.x;       // [0, 262144)
  const float4* xs = (const float4*)x;
  ushort4* xd = (ushort4*)xbf;
  float4 v0 = xs[tid];
  float4 v1 = xs[tid + 262144];
  float4 v2 = xs[tid + 524288];
  float4 v3 = xs[tid + 786432];
  xd[tid         ] = cvt4(v0);
  xd[tid + 262144] = cvt4(v1);
  xd[tid + 524288] = cvt4(v2);
  xd[tid + 786432] = cvt4(v3);
  if (tid < 196608){
    const float4* ws_ = (const float4*)W;
    ushort4* wd = (ushort4*)wbf;
    wd[tid] = cvt4(ws_[tid]);
  }
}

// ---------------- heavy: gemm + gram INTERLEAVED per XCD ----------------
// Per-XCD sequence position p = blk>>3 in [0,160): p%5<3 -> gemm (96/XCD),
// p%5>=3 -> gram (64/XCD, b = xcd, i0 by local index). Gram blocks slot into
// gemm blocks' staggered retirement gaps instead of forming a serial tail
// (R15's gram-FIRST failed by delaying gemm start; this keeps gemm 3/CU from t=0).
// gemm: C[m][row][j] = A[row,:]·W[m][j,:] + bias[m][j], tile 128x128 BK=32,
//       3-buffer rotation, counted vmcnt(4); XCD-chunked (by,bx) swizzle.
// gram: Gband[b][i][dl+14] = x[b,i]·x[b,i+dl], |dl|<=14; 48-row LDS stage.
__global__ __launch_bounds__(256) void k_heavy(const unsigned short* __restrict__ A,
    const unsigned short* __restrict__ Bw, const float* __restrict__ bias,
    unsigned short* __restrict__ C, float* __restrict__ Gband)
{
  __shared__ __align__(16) unsigned short smem[24576]; // 48KB: gemm bufs / gram rows / Ct alias
  int blk = blockIdx.x;
  int tid = threadIdx.x, lane = tid & 63, w = tid >> 6;
  int xcd = blk & 7, p = blk >> 3;          // p in [0,160)

  if (p % 5 >= 3){
    // ---- gram path: b = xcd (XCD-local xbf rows), i0 from local index ----
    int glocal = (p/5)*2 + (p%5 - 3);       // [0,64)
    int b = xcd, i0 = glocal * 16;
    #pragma unroll
    for (int q = 0; q < 12; ++q){
      int r = w*12 + q;
      int t = i0 - 16 + r;
      t = t < 0 ? 0 : (t > S_LEN-1 ? S_LEN-1 : t);
      const unsigned short* src = A + ((size_t)(t*B_N + b))*512 + ((lane ^ (r & 7))*8);
      GLL16(src, smem + r*512);
    }
    __syncthreads();   // drains vmcnt(0): staged rows visible to all waves
    int j0 = i0 + (w - 1) * 16;
    if (w < 3 && j0 >= 0 && j0 < S_LEN){
      int l15 = lane & 15;
      int cbase = lane >> 4;
      int sw = l15 & 7;
      f32x4 acc = (f32x4){0.f,0.f,0.f,0.f};
      #pragma unroll
      for (int kt = 0; kt < 16; ++kt){
        int ch = (kt*4 + cbase) ^ sw;
        short8 af = *(const short8*)(smem + (16 + l15)*512 + ch*8);
        short8 bf = *(const short8*)(smem + (w*16 + l15)*512 + ch*8);
        acc = __builtin_amdgcn_mfma_f32_16x16x32_bf16(af, bf, acc, 0,0,0);
      }
      int rb = (lane >> 4) * 4;
      #pragma unroll
      for (int rg = 0; rg < 4; ++rg){
        int i = i0 + rb + rg;
        int dl = j0 + l15 - i;
        if (dl >= -14 && dl <= 14)
          Gband[((size_t)b * S_LEN + i) * 32 + dl + 14] = acc[rg];
      }
    }
    return;
  }

  // ---- gemm path ----
  int ixc = (p/5)*3 + (p%5);                // [0,96)
  int by = xcd * 8 + ixc / 12;              // 8 A-tiles per XCD
  int bx = ixc % 12;
  int wm = w >> 1, wn = w & 1;
  int c0 = w*128 + lane, c1 = c0 + 64;
  const unsigned short* gA0 = A + (size_t)(by*128 + (c0>>2))*512 + (c0&3)*8;
  const unsigned short* gA1 = A + (size_t)(by*128 + (c1>>2))*512 + (c1&3)*8;
  const unsigned short* gB0 = Bw + (size_t)(bx*128 + (c0>>2))*512 + (c0&3)*8;
  const unsigned short* gB1 = Bw + (size_t)(bx*128 + (c1>>2))*512 + (c1&3)*8;
  f32x4 acc[4][4];
  #pragma unroll
  for (int i=0;i<4;++i)
    #pragma unroll
    for (int j=0;j<4;++j)
      acc[i][j] = (f32x4){0.f,0.f,0.f,0.f};
  int l15 = lane & 15, klo = (lane>>4)*8;
  {
    unsigned short* s0 = smem + w*1024;
    GLL16(gA0, s0); GLL16(gA1, s0 + 512);
    GLL16(gB0, s0 + 4096); GLL16(gB1, s0 + 4096 + 512);
    gA0 += 32; gA1 += 32; gB0 += 32; gB1 += 32;
    unsigned short* s1 = smem + 8192 + w*1024;
    GLL16(gA0, s1); GLL16(gA1, s1 + 512);
    GLL16(gB0, s1 + 4096); GLL16(gB1, s1 + 4096 + 512);
    gA0 += 32; gA1 += 32; gB0 += 32; gB1 += 32;
  }
  VMCNT(4); SBAR();
  #pragma unroll
  for (int kt = 0; kt < 16; ++kt){
    unsigned short* sc = smem + (kt % 3)*8192;
    if (kt + 2 < 16){
      unsigned short* sn = smem + ((kt + 2) % 3)*8192 + w*1024;
      GLL16(gA0, sn); GLL16(gA1, sn + 512);
      GLL16(gB0, sn + 4096); GLL16(gB1, sn + 4096 + 512);
      gA0 += 32; gA1 += 32; gB0 += 32; gB1 += 32;
    }
    short8 af[4], bfr[4];
    #pragma unroll
    for (int i=0;i<4;++i)
      af[i] = *(const short8*)(sc + (wm*64 + i*16 + l15)*32 + klo);
    #pragma unroll
    for (int j=0;j<4;++j)
      bfr[j] = *(const short8*)(sc + 4096 + (wn*64 + j*16 + l15)*32 + klo);
    #pragma unroll
    for (int i=0;i<4;++i)
      #pragma unroll
      for (int j=0;j<4;++j)
        acc[i][j] = __builtin_amdgcn_mfma_f32_16x16x32_bf16(af[i], bfr[j], acc[i][j], 0,0,0);
    if (kt < 15){
      __builtin_amdgcn_sched_barrier(0);
      if (kt + 2 < 16){ VMCNT(4); }
      else            { VMCNT(0); }
      SBAR();
    }
  }
  __syncthreads();
  int rbase = (lane>>4)*4;
  #pragma unroll
  for (int j=0;j<4;++j){
    int nl = wn*64 + j*16 + l15;
    float bv = bias[bx*128 + nl];
    #pragma unroll
    for (int i=0;i<4;++i){
      int rl0 = wm*64 + i*16 + rbase;
      #pragma unroll
      for (int rg=0;rg<4;++rg)
        smem[(rl0+rg)*128 + nl] = f2bf(acc[i][j][rg] + bv);
    }
  }
  __syncthreads();
  int m_r = bx >> 2, colb = (bx&3)*128;
  #pragma unroll
  for (int p2=0;p2<8;++p2){
    int R = p2*16 + (tid>>4);
    int ch = (tid&15)*8;
    uint4 v = *(const uint4*)(smem + R*128 + ch);
    *(uint4*)(C + (size_t)m_r*SLAB + (size_t)(by*128 + R)*512 + colb + ch) = v;
  }
}

// ---------------- fused weights + gather: 1 t per 128-thread block, T14 deep hoist ----
__global__ __launch_bounds__(128) void k_gath(const float* __restrict__ x,
    const unsigned short* __restrict__ tfm, const float* __restrict__ Gband,
    const float* __restrict__ alphas, const float* __restrict__ betas,
    float* __restrict__ out)
{
  int blk = blockIdx.x;           // 8192 = 8 b x 1024 t
  int b = blk & 7, t = blk >> 3;
  int j = threadIdx.x;            // [0,128)
  int d0 = j * 4;
  size_t xoff = ((size_t)t * B_N + b) * D_DIM + d0;
  float4 a = *(const float4*)(x + xoff);
  uint2 tv[33];
  #pragma unroll
  for (int p = 0; p < 33; ++p){
    int pm, pr, wsl;
    if (p < 7){ pm = 0; pr = 3; wsl = p; }
    else if (p < 18){ pm = 1; pr = 5; wsl = p - 7; }
    else { pm = 2; pr = 7; wsl = p - 18; }
    int ppos = t + wsl - pr;
    if (ppos >= 0 && ppos < S_LEN)
      tv[p] = *(const uint2*)(tfm + (size_t)pm * SLAB + ((size_t)ppos * B_N + b) * D_DIM + d0);
    else
      tv[p] = make_uint2(0u, 0u);
  }
  __shared__ float pshare[33];
  __shared__ float invc[3];
  __shared__ float wsh[33];
  int m = 0, pos = 0, valid = 0;
  float pp = 0.f, invnp = 0.f;
  if (j < 33){
    int r, wsl;
    if (j < 7){ m = 0; r = 3; wsl = j; }
    else if (j < 18){ m = 1; r = 5; wsl = j - 7; }
    else { m = 2; r = 7; wsl = j - 18; }
    pos = t + wsl - r;
    valid = (pos >= 0 && pos < S_LEN);
    if (valid){
      const float* grow = Gband + ((size_t)b * S_LEN + pos) * 32;
      int ulo = max(t - r, 0), uhi = min(t + r, S_LEN - 1);
      for (int uu = ulo; uu <= uhi; ++uu) pp += grow[uu - pos + 14];
      invnp = rsqrtf(fmaxf(grow[14], 1e-24f));
    }
    pshare[j] = valid ? pp : 0.f;
  }
  __syncthreads();
  if (j < 3){
    int s0 = j == 0 ? 0 : (j == 1 ? 7 : 18);
    int c  = j == 0 ? 7 : (j == 1 ? 11 : 15);
    float s = 0.f;
    for (int k = 0; k < c; ++k) s += pshare[s0 + k];
    invc[j] = rsqrtf(fmaxf(s, 1e-24f));
  }
  __syncthreads();
  if (j < 33){
    float wt = 0.f;
    if (valid){
      float sim = pp * invnp * invc[m];
      float z = alphas[m] * sim + betas[m];
      wt = 1.0f / (1.0f + expf(-z));
    }
    wsh[j] = wt;
  }
  __syncthreads();
  float ax = a.x, ay = a.y, az = a.z, aw = a.w;
  #pragma unroll
  for (int p = 0; p < 33; ++p){
    float wt = wsh[p];
    uint2 uv = tv[p];
    ax += wt * bf2f((unsigned short)(uv.x & 0xffffu));
    ay += wt * bf2f((unsigned short)(uv.x >> 16));
    az += wt * bf2f((unsigned short)(uv.y & 0xffffu));
    aw += wt * bf2f((unsigned short)(uv.y >> 16));
  }
  *(float4*)(out + xoff) = make_float4(ax, ay, az, aw);
}

extern "C" void kernel_launch(void* const* d_in, const int* in_sizes, int n_in,
                              void* d_out, int out_size, void* d_ws, size_t ws_size,
                              hipStream_t stream) {
  const float* x      = (const float*)d_in[0];
  const float* W      = (const float*)d_in[1];
  const float* bias   = (const float*)d_in[2];
  const float* alphas = (const float*)d_in[3];
  const float* betas  = (const float*)d_in[4];
  float* out = (float*)d_out;
  char* ws = (char*)d_ws;
  unsigned short* xbf  = (unsigned short*)ws;                               //  8,388,608 B
  unsigned short* wbf  = (unsigned short*)(ws + 8388608);                   //  1,572,864 B
  unsigned short* tfm  = (unsigned short*)(ws + 8388608 + 1572864);         // 25,165,824 B
  float*          Gband= (float*)(ws + 8388608 + 1572864 + 25165824);       //  1,048,576 B

  k_conv <<<1024, 256, 0, stream>>>(x, W, xbf, wbf);
  k_heavy<<<1280, 256, 0, stream>>>(xbf, wbf, bias, tfm, Gband);
  k_gath <<<8192, 128, 0, stream>>>(x, tfm, Gband, alphas, betas, out);
}

// Round 19
// 59.733 us; speedup vs baseline: 1.0706x; 1.0706x over previous
//
#include <hip/hip_runtime.h>

typedef __attribute__((ext_vector_type(8))) short short8;
typedef __attribute__((ext_vector_type(4))) float f32x4;

#define S_LEN 1024
#define B_N 8
#define D_DIM 512
#define SLAB 4194304    // 8192*512 elements per tfm slab
#define NX   4194304    // x element count

static __device__ __forceinline__ unsigned short f2bf(float f){
  unsigned int u = __float_as_uint(f);
  u = u + 0x7fffu + ((u>>16)&1u);
  return (unsigned short)(u>>16);
}
static __device__ __forceinline__ float bf2f(unsigned short h){
  return __uint_as_float(((unsigned int)h)<<16);
}
static __device__ __forceinline__ ushort4 cvt4(float4 v){
  ushort4 h; h.x=f2bf(v.x); h.y=f2bf(v.y); h.z=f2bf(v.z); h.w=f2bf(v.w); return h;
}

#define GLL16(g,l) __builtin_amdgcn_global_load_lds( \
    (__attribute__((address_space(1))) void*)(g), \
    (__attribute__((address_space(3))) void*)(l), 16, 0, 0)

// hard barrier: compiler memory barrier + ISA barrier + sched fence both sides
#define SBAR() do { __builtin_amdgcn_sched_barrier(0); \
  asm volatile("s_barrier" ::: "memory"); \
  __builtin_amdgcn_sched_barrier(0); } while(0)
#define VMCNT(n) asm volatile("s_waitcnt vmcnt(" #n ")" ::: "memory")

// ---------------- conv: x and W -> bf16, 4-deep ILP per thread ----------------
__global__ __launch_bounds__(256) void k_conv(const float* __restrict__ x,
    const float* __restrict__ W, unsigned short* __restrict__ xbf,
    unsigned short* __restrict__ wbf)
{
  int tid = blockIdx.x*256 + threadIdx.x;       // [0, 262144)
  const float4* xs = (const float4*)x;
  ushort4* xd = (ushort4*)xbf;
  float4 v0 = xs[tid];
  float4 v1 = xs[tid + 262144];
  float4 v2 = xs[tid + 524288];
  float4 v3 = xs[tid + 786432];
  xd[tid         ] = cvt4(v0);
  xd[tid + 262144] = cvt4(v1);
  xd[tid + 524288] = cvt4(v2);
  xd[tid + 786432] = cvt4(v3);
  if (tid < 196608){
    const float4* ws_ = (const float4*)W;
    ushort4* wd = (ushort4*)wbf;
    wd[tid] = cvt4(ws_[tid]);
  }
}

// ---------------- heavy: gemm blocks [0,768) + gram blocks [768,1280) ----------------
// (R14/R17 proven-best config: gemm first, gram as tail)
__global__ __launch_bounds__(256) void k_heavy(const unsigned short* __restrict__ A,
    const unsigned short* __restrict__ Bw, const float* __restrict__ bias,
    unsigned short* __restrict__ C, float* __restrict__ Gband)
{
  __shared__ __align__(16) unsigned short smem[24576]; // 48KB: gemm bufs / gram rows / Ct alias
  int blk = blockIdx.x;
  int tid = threadIdx.x, lane = tid & 63, w = tid >> 6;

  if (blk >= 768){
    // ---- gram path: stage 48 rows, then 3 waves x 16 MFMA from LDS ----
    int g = blk - 768;
    int b = g & 7, i0 = (g >> 3) * 16;
    #pragma unroll
    for (int q = 0; q < 12; ++q){
      int r = w*12 + q;
      int t = i0 - 16 + r;
      t = t < 0 ? 0 : (t > S_LEN-1 ? S_LEN-1 : t);
      const unsigned short* src = A + ((size_t)(t*B_N + b))*512 + ((lane ^ (r & 7))*8);
      GLL16(src, smem + r*512);
    }
    __syncthreads();   // drains vmcnt(0): staged rows visible to all waves
    int j0 = i0 + (w - 1) * 16;
    if (w < 3 && j0 >= 0 && j0 < S_LEN){
      int l15 = lane & 15;
      int cbase = lane >> 4;
      int sw = l15 & 7;
      f32x4 acc = (f32x4){0.f,0.f,0.f,0.f};
      #pragma unroll
      for (int kt = 0; kt < 16; ++kt){
        int ch = (kt*4 + cbase) ^ sw;
        short8 af = *(const short8*)(smem + (16 + l15)*512 + ch*8);
        short8 bf = *(const short8*)(smem + (w*16 + l15)*512 + ch*8);
        acc = __builtin_amdgcn_mfma_f32_16x16x32_bf16(af, bf, acc, 0,0,0);
      }
      int rb = (lane >> 4) * 4;
      #pragma unroll
      for (int rg = 0; rg < 4; ++rg){
        int i = i0 + rb + rg;
        int dl = j0 + l15 - i;
        if (dl >= -14 && dl <= 14)
          Gband[((size_t)b * S_LEN + i) * 32 + dl + 14] = acc[rg];
      }
    }
    return;
  }

  // ---- gemm path ----
  int xcd = blk & 7, ixc = blk >> 3;        // ixc in [0,96)
  int by = xcd * 8 + ixc / 12;              // 8 A-tiles per XCD
  int bx = ixc % 12;
  int wm = w >> 1, wn = w & 1;
  int c0 = w*128 + lane, c1 = c0 + 64;
  const unsigned short* gA0 = A + (size_t)(by*128 + (c0>>2))*512 + (c0&3)*8;
  const unsigned short* gA1 = A + (size_t)(by*128 + (c1>>2))*512 + (c1&3)*8;
  const unsigned short* gB0 = Bw + (size_t)(bx*128 + (c0>>2))*512 + (c0&3)*8;
  const unsigned short* gB1 = Bw + (size_t)(bx*128 + (c1>>2))*512 + (c1&3)*8;
  f32x4 acc[4][4];
  #pragma unroll
  for (int i=0;i<4;++i)
    #pragma unroll
    for (int j=0;j<4;++j)
      acc[i][j] = (f32x4){0.f,0.f,0.f,0.f};
  int l15 = lane & 15, klo = (lane>>4)*8;
  {
    unsigned short* s0 = smem + w*1024;
    GLL16(gA0, s0); GLL16(gA1, s0 + 512);
    GLL16(gB0, s0 + 4096); GLL16(gB1, s0 + 4096 + 512);
    gA0 += 32; gA1 += 32; gB0 += 32; gB1 += 32;
    unsigned short* s1 = smem + 8192 + w*1024;
    GLL16(gA0, s1); GLL16(gA1, s1 + 512);
    GLL16(gB0, s1 + 4096); GLL16(gB1, s1 + 4096 + 512);
    gA0 += 32; gA1 += 32; gB0 += 32; gB1 += 32;
  }
  VMCNT(4); SBAR();
  #pragma unroll
  for (int kt = 0; kt < 16; ++kt){
    unsigned short* sc = smem + (kt % 3)*8192;
    if (kt + 2 < 16){
      unsigned short* sn = smem + ((kt + 2) % 3)*8192 + w*1024;
      GLL16(gA0, sn); GLL16(gA1, sn + 512);
      GLL16(gB0, sn + 4096); GLL16(gB1, sn + 4096 + 512);
      gA0 += 32; gA1 += 32; gB0 += 32; gB1 += 32;
    }
    short8 af[4], bfr[4];
    #pragma unroll
    for (int i=0;i<4;++i)
      af[i] = *(const short8*)(sc + (wm*64 + i*16 + l15)*32 + klo);
    #pragma unroll
    for (int j=0;j<4;++j)
      bfr[j] = *(const short8*)(sc + 4096 + (wn*64 + j*16 + l15)*32 + klo);
    #pragma unroll
    for (int i=0;i<4;++i)
      #pragma unroll
      for (int j=0;j<4;++j)
        acc[i][j] = __builtin_amdgcn_mfma_f32_16x16x32_bf16(af[i], bfr[j], acc[i][j], 0,0,0);
    if (kt < 15){
      __builtin_amdgcn_sched_barrier(0);
      if (kt + 2 < 16){ VMCNT(4); }
      else            { VMCNT(0); }
      SBAR();
    }
  }
  __syncthreads();
  int rbase = (lane>>4)*4;
  #pragma unroll
  for (int j=0;j<4;++j){
    int nl = wn*64 + j*16 + l15;
    float bv = bias[bx*128 + nl];
    #pragma unroll
    for (int i=0;i<4;++i){
      int rl0 = wm*64 + i*16 + rbase;
      #pragma unroll
      for (int rg=0;rg<4;++rg)
        smem[(rl0+rg)*128 + nl] = f2bf(acc[i][j][rg] + bv);
    }
  }
  __syncthreads();
  int m_r = bx >> 2, colb = (bx&3)*128;
  #pragma unroll
  for (int p=0;p<8;++p){
    int R = p*16 + (tid>>4);
    int ch = (tid&15)*8;
    uint4 v = *(const uint4*)(smem + R*128 + ch);
    *(uint4*)(C + (size_t)m_r*SLAB + (size_t)(by*128 + R)*512 + colb + ch) = v;
  }
}

// ---------------- fused weights + gather: 1 t per 128-thread block, T14 deep hoist ----
__global__ __launch_bounds__(128) void k_gath(const float* __restrict__ x,
    const unsigned short* __restrict__ tfm, const float* __restrict__ Gband,
    const float* __restrict__ alphas, const float* __restrict__ betas,
    float* __restrict__ out)
{
  int blk = blockIdx.x;           // 8192 = 8 b x 1024 t
  int b = blk & 7, t = blk >> 3;
  int j = threadIdx.x;            // [0,128)
  int d0 = j * 4;
  size_t xoff = ((size_t)t * B_N + b) * D_DIM + d0;
  float4 a = *(const float4*)(x + xoff);
  uint2 tv[33];
  #pragma unroll
  for (int p = 0; p < 33; ++p){
    int pm, pr, wsl;
    if (p < 7){ pm = 0; pr = 3; wsl = p; }
    else if (p < 18){ pm = 1; pr = 5; wsl = p - 7; }
    else { pm = 2; pr = 7; wsl = p - 18; }
    int ppos = t + wsl - pr;
    if (ppos >= 0 && ppos < S_LEN)
      tv[p] = *(const uint2*)(tfm + (size_t)pm * SLAB + ((size_t)ppos * B_N + b) * D_DIM + d0);
    else
      tv[p] = make_uint2(0u, 0u);
  }
  __shared__ float pshare[33];
  __shared__ float invc[3];
  __shared__ float wsh[33];
  int m = 0, pos = 0, valid = 0;
  float pp = 0.f, invnp = 0.f;
  if (j < 33){
    int r, wsl;
    if (j < 7){ m = 0; r = 3; wsl = j; }
    else if (j < 18){ m = 1; r = 5; wsl = j - 7; }
    else { m = 2; r = 7; wsl = j - 18; }
    pos = t + wsl - r;
    valid = (pos >= 0 && pos < S_LEN);
    if (valid){
      const float* grow = Gband + ((size_t)b * S_LEN + pos) * 32;
      int ulo = max(t - r, 0), uhi = min(t + r, S_LEN - 1);
      for (int uu = ulo; uu <= uhi; ++uu) pp += grow[uu - pos + 14];
      invnp = rsqrtf(fmaxf(grow[14], 1e-24f));
    }
    pshare[j] = valid ? pp : 0.f;
  }
  __syncthreads();
  if (j < 3){
    int s0 = j == 0 ? 0 : (j == 1 ? 7 : 18);
    int c  = j == 0 ? 7 : (j == 1 ? 11 : 15);
    float s = 0.f;
    for (int k = 0; k < c; ++k) s += pshare[s0 + k];
    invc[j] = rsqrtf(fmaxf(s, 1e-24f));
  }
  __syncthreads();
  if (j < 33){
    float wt = 0.f;
    if (valid){
      float sim = pp * invnp * invc[m];
      float z = alphas[m] * sim + betas[m];
      wt = 1.0f / (1.0f + expf(-z));
    }
    wsh[j] = wt;
  }
  __syncthreads();
  float ax = a.x, ay = a.y, az = a.z, aw = a.w;
  #pragma unroll
  for (int p = 0; p < 33; ++p){
    float wt = wsh[p];
    uint2 uv = tv[p];
    ax += wt * bf2f((unsigned short)(uv.x & 0xffffu));
    ay += wt * bf2f((unsigned short)(uv.x >> 16));
    az += wt * bf2f((unsigned short)(uv.y & 0xffffu));
    aw += wt * bf2f((unsigned short)(uv.y >> 16));
  }
  *(float4*)(out + xoff) = make_float4(ax, ay, az, aw);
}

extern "C" void kernel_launch(void* const* d_in, const int* in_sizes, int n_in,
                              void* d_out, int out_size, void* d_ws, size_t ws_size,
                              hipStream_t stream) {
  const float* x      = (const float*)d_in[0];
  const float* W      = (const float*)d_in[1];
  const float* bias   = (const float*)d_in[2];
  const float* alphas = (const float*)d_in[3];
  const float* betas  = (const float*)d_in[4];
  float* out = (float*)d_out;
  char* ws = (char*)d_ws;
  unsigned short* xbf  = (unsigned short*)ws;                               //  8,388,608 B
  unsigned short* wbf  = (unsigned short*)(ws + 8388608);                   //  1,572,864 B
  unsigned short* tfm  = (unsigned short*)(ws + 8388608 + 1572864);         // 25,165,824 B
  float*          Gband= (float*)(ws + 8388608 + 1572864 + 25165824);       //  1,048,576 B

  k_conv <<<1024, 256, 0, stream>>>(x, W, xbf, wbf);
  k_heavy<<<1280, 256, 0, stream>>>(xbf, wbf, bias, tfm, Gband);
  k_gath <<<8192, 128, 0, stream>>>(x, tfm, Gband, alphas, betas, out);
}